// Round 1
// baseline (7072.533 us; speedup 1.0000x reference)
//
#include <hip/hip_runtime.h>

#define NN 16000   // nodes
#define NE 64000   // edges
#define HD 90      // hidden
#define NG 512     // graphs

// h0 = concat(x, pos) : [NN, 16]
__global__ void concat_kernel(const float* __restrict__ x, const float* __restrict__ pos,
                              float* __restrict__ h0) {
  int idx = blockIdx.x * 256 + threadIdx.x;
  if (idx >= NN * 16) return;
  int n = idx >> 4, c = idx & 15;
  h0[idx] = (c < 13) ? x[n * 13 + c] : pos[n * 3 + (c - 13)];
}

// he[e][k] = relu(b1[k] + sum_j ea[e][j] * w1[j][k]) : [NE, 90]
__global__ void edge_mlp_kernel(const float* __restrict__ ea, const float* __restrict__ w1,
                                const float* __restrict__ b1, float* __restrict__ he) {
  int idx = blockIdx.x * 256 + threadIdx.x;
  if (idx >= NE * HD) return;
  int e = idx / HD, k = idx - e * HD;
  const float* a = ea + e * 8;
  float acc = b1[k];
#pragma unroll
  for (int j = 0; j < 8; j++) acc = fmaf(a[j], w1[j * HD + k], acc);
  he[idx] = fmaxf(acc, 0.f);
}

// Fused message GEMM + scatter:
//   msg[e][o] = sum_{k<90,i} he[e][k]*z[e][i]*w2[k, i*OC+o] + sum_i z[e][i]*b2[i*OC+o]
//   atomicAdd into agg[dst[e]][o]
// K index = k*IN_C + i, k in [0,91) with virtual h-row k=90 == 1.0 (bias fold).
// Block: 64 edges, 256 threads (16x16): thread = 4 edges (ty) x ON channels (tx, o = tx+16j).
template <int IN_C, int OC, int ON>
__launch_bounds__(256, 2)
__global__ void msg_kernel(const float* __restrict__ he, const float* __restrict__ nin,
                           const int* __restrict__ src, const int* __restrict__ dst,
                           const float* __restrict__ w2, const float* __restrict__ b2,
                           float* __restrict__ agg) {
  constexpr int OCP = ON * 16;          // padded OC (96 or 48)
  constexpr int KTOT = 91 * IN_C;       // includes bias row
  constexpr int KB = 16;
  constexpr int NCHUNK = (KTOT + KB - 1) / KB;
  constexpr int ES = 68;                // edge stride: 64 + 4 pad (16B-aligned rows, conflict-light)
  __shared__ float h_sT[92 * ES];       // [k][e], rows 90=ones 91=zeros
  __shared__ float z_sT[IN_C * ES];     // [i][e]
  __shared__ float w_s[KB * OCP];       // [kk][o]
  const int tid = threadIdx.x;
  const int tx = tid & 15, ty = tid >> 4;
  const int e0 = blockIdx.x * 64;

  // stage he (transposed); global reads fully coalesced
  for (int i = tid; i < 64 * HD; i += 256) {
    int e = i / HD, k = i - e * HD;
    h_sT[k * ES + e] = he[e0 * HD + i];
  }
  if (tid < 64) { h_sT[90 * ES + tid] = 1.f; h_sT[91 * ES + tid] = 0.f; }
  // gather z = nin[src[e]]
  for (int i = tid; i < 64 * IN_C; i += 256) {
    int e = i / IN_C, c = i - e * IN_C;
    z_sT[c * ES + e] = nin[src[e0 + e] * IN_C + c];
  }

  float acc[4][ON];
#pragma unroll
  for (int m = 0; m < 4; m++)
#pragma unroll
    for (int j = 0; j < ON; j++) acc[m][j] = 0.f;

  int k_hi = 0, k_lo = 0;  // kidx = k_hi*IN_C + k_lo, tracked incrementally (uniform)
  for (int chunk = 0; chunk < NCHUNK; chunk++) {
    const int kb = chunk * KB;
    __syncthreads();
    // stage w2 chunk rows [kb, kb+16) ; zero pads and out-of-range rows
    for (int i = tid; i < KB * OCP; i += 256) {
      int kk = i / OCP, o = i - kk * OCP;
      int kidx = kb + kk;
      float v = 0.f;
      if (o < OC && kidx < KTOT) {
        int k = kidx / IN_C, ii = kidx - k * IN_C;
        v = (k < HD) ? w2[k * (IN_C * OC) + ii * OC + o] : b2[ii * OC + o];
      }
      w_s[kk * OCP + o] = v;
    }
    __syncthreads();
#pragma unroll
    for (int kk = 0; kk < KB; kk++) {
      const float4 hv = *(const float4*)&h_sT[k_hi * ES + (ty << 2)];
      const float4 zv = *(const float4*)&z_sT[k_lo * ES + (ty << 2)];
      const float u0 = hv.x * zv.x, u1 = hv.y * zv.y, u2 = hv.z * zv.z, u3 = hv.w * zv.w;
#pragma unroll
      for (int j = 0; j < ON; j++) {
        const float w = w_s[kk * OCP + tx + 16 * j];
        acc[0][j] = fmaf(u0, w, acc[0][j]);
        acc[1][j] = fmaf(u1, w, acc[1][j]);
        acc[2][j] = fmaf(u2, w, acc[2][j]);
        acc[3][j] = fmaf(u3, w, acc[3][j]);
      }
      if (++k_lo == IN_C) { k_lo = 0; ++k_hi; }
    }
  }
  // scatter-add to agg[dst]
#pragma unroll
  for (int m = 0; m < 4; m++) {
    int e = e0 + (ty << 2) + m;
    float* ap = agg + dst[e] * OC;
#pragma unroll
    for (int j = 0; j < ON; j++) {
      int o = tx + 16 * j;
      if (o < OC) atomicAdd(ap + o, acc[m][j]);
    }
  }
}

// out[n][o] = relu(agg[n][o] + sum_i nin[n][i]*root[i][o] + bias[o])
template <int IN_C, int OC>
__global__ void node_kernel(const float* __restrict__ agg, const float* __restrict__ nin,
                            const float* __restrict__ root, const float* __restrict__ bias,
                            float* __restrict__ out) {
  int idx = blockIdx.x * 256 + threadIdx.x;
  if (idx >= NN * OC) return;
  int n = idx / OC, o = idx - n * OC;
  float acc = agg[idx] + bias[o];
  const float* inp = nin + n * IN_C;
#pragma unroll 6
  for (int i = 0; i < IN_C; i++) acc = fmaf(inp[i], root[i * OC + o], acc);
  out[idx] = fmaxf(acc, 0.f);
}

// per-graph: pool (batch sorted -> binary search) + fc1 + out
__global__ void pool_mlp_kernel(const float* __restrict__ h3, const int* __restrict__ batch,
                                const float* __restrict__ fc1_w, const float* __restrict__ fc1_b,
                                const float* __restrict__ out_w, const float* __restrict__ out_b,
                                float* __restrict__ out) {
  const int b = blockIdx.x;
  const int tid = threadIdx.x;
  __shared__ float g[45];
  __shared__ float go[90];
  __shared__ int rng[2];
  if (tid < 2) {
    int target = b + tid;  // lower_bound(batch, target)
    int lo = 0, hi = NN;
    while (lo < hi) { int mid = (lo + hi) >> 1; if (batch[mid] < target) lo = mid + 1; else hi = mid; }
    rng[tid] = lo;
  }
  __syncthreads();
  const int s = rng[0], e = rng[1];
  if (tid < 45) {
    float acc = 0.f;
    for (int n = s; n < e; n++) acc += h3[n * 45 + tid];
    g[tid] = acc;
  }
  __syncthreads();
  if (tid < 90) {
    float acc = fc1_b[tid];
#pragma unroll 5
    for (int i = 0; i < 45; i++) acc = fmaf(g[i], fc1_w[i * 90 + tid], acc);
    go[tid] = fmaxf(acc, 0.f) * out_w[tid];
  }
  __syncthreads();
  if (tid == 0) {
    float acc = out_b[0];
    for (int i = 0; i < 90; i++) acc += go[i];
    out[b] = acc;
  }
}

extern "C" void kernel_launch(void* const* d_in, const int* in_sizes, int n_in,
                              void* d_out, int out_size, void* d_ws, size_t ws_size,
                              hipStream_t stream) {
  const float* x       = (const float*)d_in[0];
  const float* pos     = (const float*)d_in[1];
  const float* ea      = (const float*)d_in[2];
  const int*   eidx    = (const int*)d_in[3];
  const int*   batch   = (const int*)d_in[4];
  const float* c1_w1   = (const float*)d_in[5];
  const float* c1_b1   = (const float*)d_in[6];
  const float* c1_w2   = (const float*)d_in[7];
  const float* c1_b2   = (const float*)d_in[8];
  const float* c1_root = (const float*)d_in[9];
  const float* c1_bias = (const float*)d_in[10];
  const float* c2_w1   = (const float*)d_in[11];
  const float* c2_b1   = (const float*)d_in[12];
  const float* c2_w2   = (const float*)d_in[13];
  const float* c2_b2   = (const float*)d_in[14];
  const float* c2_root = (const float*)d_in[15];
  const float* c2_bias = (const float*)d_in[16];
  const float* c3_w1   = (const float*)d_in[17];
  const float* c3_b1   = (const float*)d_in[18];
  const float* c3_w2   = (const float*)d_in[19];
  const float* c3_b2   = (const float*)d_in[20];
  const float* c3_root = (const float*)d_in[21];
  const float* c3_bias = (const float*)d_in[22];
  const float* fc1_w   = (const float*)d_in[23];
  const float* fc1_b   = (const float*)d_in[24];
  const float* out_w   = (const float*)d_in[25];
  const float* out_b   = (const float*)d_in[26];
  const int* src = eidx;
  const int* dst = eidx + NE;

  float* ws  = (float*)d_ws;
  float* h0  = ws;               // NN*16
  float* h1  = h0 + NN * 16;     // NN*90
  float* h2  = h1 + NN * 90;     // NN*90
  float* h3  = h2 + NN * 90;     // NN*45
  float* he  = h3 + NN * 45;     // NE*90
  float* agg = he + NE * 90;     // NN*90  (total ~44 MB)

  concat_kernel<<<(NN * 16) / 256, 256, 0, stream>>>(x, pos, h0);

  // conv1: 16 -> 90
  hipMemsetAsync(agg, 0, (size_t)NN * 90 * sizeof(float), stream);
  edge_mlp_kernel<<<(NE * HD) / 256, 256, 0, stream>>>(ea, c1_w1, c1_b1, he);
  msg_kernel<16, 90, 6><<<NE / 64, 256, 0, stream>>>(he, h0, src, dst, c1_w2, c1_b2, agg);
  node_kernel<16, 90><<<(NN * 90) / 256, 256, 0, stream>>>(agg, h0, c1_root, c1_bias, h1);

  // conv2: 90 -> 90
  hipMemsetAsync(agg, 0, (size_t)NN * 90 * sizeof(float), stream);
  edge_mlp_kernel<<<(NE * HD) / 256, 256, 0, stream>>>(ea, c2_w1, c2_b1, he);
  msg_kernel<90, 90, 6><<<NE / 64, 256, 0, stream>>>(he, h1, src, dst, c2_w2, c2_b2, agg);
  node_kernel<90, 90><<<(NN * 90) / 256, 256, 0, stream>>>(agg, h1, c2_root, c2_bias, h2);

  // conv3: 90 -> 45
  hipMemsetAsync(agg, 0, (size_t)NN * 45 * sizeof(float), stream);
  edge_mlp_kernel<<<(NE * HD) / 256, 256, 0, stream>>>(ea, c3_w1, c3_b1, he);
  msg_kernel<90, 45, 3><<<NE / 64, 256, 0, stream>>>(he, h2, src, dst, c3_w2, c3_b2, agg);
  node_kernel<90, 45><<<(NN * 45 + 255) / 256, 256, 0, stream>>>(agg, h2, c3_root, c3_bias, h3);

  pool_mlp_kernel<<<NG, 128, 0, stream>>>(h3, batch, fc1_w, fc1_b, out_w, out_b, (float*)d_out);
}

// Round 2
// 1343.025 us; speedup vs baseline: 5.2661x; 5.2661x over previous
//
#include <hip/hip_runtime.h>

#define NN 16000   // nodes
#define NE 64000   // edges
#define HD 90      // hidden
#define NG 512     // graphs

typedef float f32x4 __attribute__((ext_vector_type(4)));
typedef short s16x8 __attribute__((ext_vector_type(8)));

// round-half-up f32 -> bf16 (unbiased enough; truncation would bias sums low)
__device__ __forceinline__ unsigned short rhu1(float f) {
  return (unsigned short)((__builtin_bit_cast(unsigned int, f) + 0x8000u) >> 16);
}
// pack two f32 -> bf16x2 (lo in low half), RHU rounding, v_perm idiom
__device__ __forceinline__ unsigned int rhu_pack(float lo, float hi) {
  unsigned int ul = __builtin_bit_cast(unsigned int, lo) + 0x8000u;
  unsigned int uh = __builtin_bit_cast(unsigned int, hi) + 0x8000u;
  return __builtin_amdgcn_perm(uh, ul, 0x07060302u);  // [uh.b3 uh.b2 ul.b3 ul.b2]
}
__device__ __forceinline__ float bf2f(unsigned short b) {
  return __builtin_bit_cast(float, ((unsigned int)b) << 16);
}

__device__ __forceinline__ void async_cp16(void* lds, const void* g) {
  __builtin_amdgcn_global_load_lds(
      (const __attribute__((address_space(1))) void*)g,
      (__attribute__((address_space(3))) void*)lds, 16, 0, 0);
}

// h0 = concat(x, pos) : [NN, 16]
__global__ void concat_kernel(const float* __restrict__ x, const float* __restrict__ pos,
                              float* __restrict__ h0) {
  int idx = blockIdx.x * 256 + threadIdx.x;
  if (idx >= NN * 16) return;
  int n = idx >> 4, c = idx & 15;
  h0[idx] = (c < 13) ? x[n * 13 + c] : pos[n * 3 + (c - 13)];
}

// he_bf[e][k] : [NE, 96] bf16. k<90: relu(edge MLP); k==90: 1.0 (bias row); k>90: 0
__global__ void edge_mlp_bf(const float* __restrict__ ea, const float* __restrict__ w1,
                            const float* __restrict__ b1, unsigned short* __restrict__ he) {
  int idx = blockIdx.x * 256 + threadIdx.x;
  if (idx >= NE * 96) return;
  int e = idx / 96, k = idx - e * 96;
  unsigned short v;
  if (k < 90) {
    const float* a = ea + e * 8;
    float acc = b1[k];
#pragma unroll
    for (int j = 0; j < 8; j++) acc = fmaf(a[j], w1[j * HD + k], acc);
    v = rhu1(fmaxf(acc, 0.f));
  } else {
    v = (k == 90) ? (unsigned short)0x3F80 : (unsigned short)0;  // bf16(1.0) / 0
  }
  he[idx] = v;
}

// W' prep: chunk-major bf16 [NC][OCP][40]; element (c,o,kk): k=c*32+kk (kk<32),
// i=k/96, hk=k%96; val = hk<90 ? w2[hk][i*OC+o] : hk==90 ? b2[i*OC+o] : 0
__global__ void wprep_kernel(const float* __restrict__ w2, const float* __restrict__ b2,
                             unsigned short* __restrict__ wout,
                             int IN_C, int OC, int OCP, int nelem) {
  int idx = blockIdx.x * 256 + threadIdx.x;
  if (idx >= nelem) return;
  int row = OCP * 40;
  int c = idx / row, r = idx - c * row;
  int o = r / 40, kk = r - o * 40;
  float v = 0.f;
  if (kk < 32 && o < OC) {
    int k = c * 32 + kk;
    int i = k / 96, hk = k - i * 96;
    if (hk < 90) v = w2[hk * (IN_C * OC) + i * OC + o];
    else if (hk == 90) v = b2[i * OC + o];
  }
  wout[idx] = rhu1(v);
}

// Fused message GEMM (bf16 MFMA) + scatter.
// Block: 128 edges x OCP outputs; 4 waves; wave = WM m-tiles(16e) x 3 n-tiles(16o).
// K' = i*96 + hk; A[e][k'] = he[e][hk] * z[e][i] built per-step from register-resident
// unpacked he frags x z scalar. W' streamed double-buffered via global_load_lds.
template <int IN_C, int OC, int OCP, int WNV, int WM, int ZSW, int NC>
__launch_bounds__(256, 2)
__global__ void msg_mfma(const unsigned short* __restrict__ he,
                         const float* __restrict__ nin,
                         const int* __restrict__ src, const int* __restrict__ dst,
                         const unsigned short* __restrict__ wp,
                         float* __restrict__ agg) {
  constexpr int WB = OCP * 40 * 2;   // bytes per W chunk (incl. 8-col pad)
  __shared__ unsigned short z_s[128 * ZSW];
  __shared__ unsigned short w_s[2][OCP * 40];
  __shared__ int dst_s[128];
  const int tid = threadIdx.x;
  const int e0 = blockIdx.x * 128;
  const int wid = tid >> 6, ln = tid & 15, q = (tid & 63) >> 4;
  const int wn = wid % WNV, wm = wid / WNV;
  const int eb = wm * (WM * 16);
  const int n0w = wn * 48;

  if (tid < 128) dst_s[tid] = dst[e0 + tid];

  // gather z = nin[src[e]] -> bf16 rows [128][ZSW]
  constexpr int PAIRS = IN_C / 2;
  for (int i2 = tid; i2 < 128 * PAIRS; i2 += 256) {
    int e = i2 / PAIRS, p = i2 - e * PAIRS;
    const float2 v = *(const float2*)(nin + (size_t)src[e0 + e] * IN_C + 2 * p);
    *(unsigned int*)&z_s[e * ZSW + 2 * p] = rhu_pack(v.x, v.y);
  }
  // stage W chunk 0 (async direct-to-LDS)
  for (int t = tid; t < WB / 16; t += 256)
    async_cp16((char*)&w_s[0][0] + t * 16, (const char*)wp + t * 16);

  // he fragments: load once from global, unpack bf16 -> f32 registers
  float hf[WM][3][8];
#pragma unroll
  for (int mt = 0; mt < WM; mt++) {
    const unsigned short* hrow = he + (size_t)(e0 + eb + mt * 16 + ln) * 96;
#pragma unroll
    for (int sub = 0; sub < 3; sub++) {
      const uint4 u = *(const uint4*)(hrow + sub * 32 + q * 8);
      hf[mt][sub][0] = __builtin_bit_cast(float, u.x << 16);
      hf[mt][sub][1] = __builtin_bit_cast(float, u.x & 0xFFFF0000u);
      hf[mt][sub][2] = __builtin_bit_cast(float, u.y << 16);
      hf[mt][sub][3] = __builtin_bit_cast(float, u.y & 0xFFFF0000u);
      hf[mt][sub][4] = __builtin_bit_cast(float, u.z << 16);
      hf[mt][sub][5] = __builtin_bit_cast(float, u.z & 0xFFFF0000u);
      hf[mt][sub][6] = __builtin_bit_cast(float, u.w << 16);
      hf[mt][sub][7] = __builtin_bit_cast(float, u.w & 0xFFFF0000u);
    }
  }
  __syncthreads();   // z_s + w_s[0] ready (barrier drains vmcnt)

  f32x4 acc[WM][3];
#pragma unroll
  for (int mt = 0; mt < WM; mt++)
#pragma unroll
    for (int nt = 0; nt < 3; nt++) acc[mt][nt] = (f32x4)0.f;

  float zf[WM];
  for (int c = 0; c < NC; c++) {
    const int buf = c & 1;
    if (c + 1 < NC) {   // prefetch next chunk into other buffer
      const char* wg = (const char*)wp + (size_t)(c + 1) * WB;
      for (int t = tid; t < WB / 16; t += 256)
        async_cp16((char*)&w_s[buf ^ 1][0] + t * 16, wg + t * 16);
    }
    const int sub = c % 3;
    if (sub == 0) {
      const int i = c / 3;
#pragma unroll
      for (int mt = 0; mt < WM; mt++)
        zf[mt] = bf2f(z_s[(eb + mt * 16 + ln) * ZSW + i]);
    }
    // A-frags: he_frag * z, RHU-round, pack
    union { unsigned int u[4]; s16x8 v; } af[WM];
#pragma unroll
    for (int mt = 0; mt < WM; mt++) {
#pragma unroll
      for (int t = 0; t < 4; t++)
        af[mt].u[t] = rhu_pack(hf[mt][sub][2 * t] * zf[mt], hf[mt][sub][2 * t + 1] * zf[mt]);
    }
#pragma unroll
    for (int nt = 0; nt < 3; nt++) {
      const s16x8 bfr = *(const s16x8*)&w_s[buf][(n0w + nt * 16 + ln) * 40 + q * 8];
#pragma unroll
      for (int mt = 0; mt < WM; mt++)
        acc[mt][nt] = __builtin_amdgcn_mfma_f32_16x16x32_bf16(af[mt].v, bfr, acc[mt][nt], 0, 0, 0);
    }
    __syncthreads();   // all reads of w_s[buf] done; prefetch landed
  }

  // epilogue: D[row=q*4+r][col=ln] -> atomicAdd agg[dst]
#pragma unroll
  for (int mt = 0; mt < WM; mt++) {
#pragma unroll
    for (int nt = 0; nt < 3; nt++) {
      int o = n0w + nt * 16 + ln;
      if (o < OC) {
#pragma unroll
        for (int r = 0; r < 4; r++) {
          int el = eb + mt * 16 + q * 4 + r;
          atomicAdd(agg + (size_t)dst_s[el] * OC + o, acc[mt][nt][r]);
        }
      }
    }
  }
}

// out[n][o] = relu(agg[n][o] + sum_i nin[n][i]*root[i][o] + bias[o])   (fp32 exact)
template <int IN_C, int OC>
__global__ void node_kernel(const float* __restrict__ agg, const float* __restrict__ nin,
                            const float* __restrict__ root, const float* __restrict__ bias,
                            float* __restrict__ out) {
  int idx = blockIdx.x * 256 + threadIdx.x;
  if (idx >= NN * OC) return;
  int n = idx / OC, o = idx - n * OC;
  float acc = agg[idx] + bias[o];
  const float* inp = nin + (size_t)n * IN_C;
#pragma unroll 6
  for (int i = 0; i < IN_C; i++) acc = fmaf(inp[i], root[i * OC + o], acc);
  out[idx] = fmaxf(acc, 0.f);
}

// per-graph: pool (batch sorted -> binary search) + fc1 + out
__global__ void pool_mlp_kernel(const float* __restrict__ h3, const int* __restrict__ batch,
                                const float* __restrict__ fc1_w, const float* __restrict__ fc1_b,
                                const float* __restrict__ out_w, const float* __restrict__ out_b,
                                float* __restrict__ out) {
  const int b = blockIdx.x;
  const int tid = threadIdx.x;
  __shared__ float g[45];
  __shared__ float go[90];
  __shared__ int rng[2];
  if (tid < 2) {
    int target = b + tid;
    int lo = 0, hi = NN;
    while (lo < hi) { int mid = (lo + hi) >> 1; if (batch[mid] < target) lo = mid + 1; else hi = mid; }
    rng[tid] = lo;
  }
  __syncthreads();
  const int s = rng[0], e = rng[1];
  if (tid < 45) {
    float acc = 0.f;
    for (int n = s; n < e; n++) acc += h3[n * 45 + tid];
    g[tid] = acc;
  }
  __syncthreads();
  if (tid < 90) {
    float acc = fc1_b[tid];
#pragma unroll 5
    for (int i = 0; i < 45; i++) acc = fmaf(g[i], fc1_w[i * 90 + tid], acc);
    go[tid] = fmaxf(acc, 0.f) * out_w[tid];
  }
  __syncthreads();
  if (tid == 0) {
    float acc = out_b[0];
    for (int i = 0; i < 90; i++) acc += go[i];
    out[b] = acc;
  }
}

extern "C" void kernel_launch(void* const* d_in, const int* in_sizes, int n_in,
                              void* d_out, int out_size, void* d_ws, size_t ws_size,
                              hipStream_t stream) {
  const float* x       = (const float*)d_in[0];
  const float* pos     = (const float*)d_in[1];
  const float* ea      = (const float*)d_in[2];
  const int*   eidx    = (const int*)d_in[3];
  const int*   batch   = (const int*)d_in[4];
  const float* c1_w1   = (const float*)d_in[5];
  const float* c1_b1   = (const float*)d_in[6];
  const float* c1_w2   = (const float*)d_in[7];
  const float* c1_b2   = (const float*)d_in[8];
  const float* c1_root = (const float*)d_in[9];
  const float* c1_bias = (const float*)d_in[10];
  const float* c2_w1   = (const float*)d_in[11];
  const float* c2_b1   = (const float*)d_in[12];
  const float* c2_w2   = (const float*)d_in[13];
  const float* c2_b2   = (const float*)d_in[14];
  const float* c2_root = (const float*)d_in[15];
  const float* c2_bias = (const float*)d_in[16];
  const float* c3_w1   = (const float*)d_in[17];
  const float* c3_b1   = (const float*)d_in[18];
  const float* c3_w2   = (const float*)d_in[19];
  const float* c3_b2   = (const float*)d_in[20];
  const float* c3_root = (const float*)d_in[21];
  const float* c3_bias = (const float*)d_in[22];
  const float* fc1_w   = (const float*)d_in[23];
  const float* fc1_b   = (const float*)d_in[24];
  const float* out_w   = (const float*)d_in[25];
  const float* out_b   = (const float*)d_in[26];
  const int* src = eidx;
  const int* dst = eidx + NE;

  // workspace carve (f32 units, then u16 region)
  float* ws  = (float*)d_ws;
  float* h0  = ws;                       // NN*16
  float* h1  = h0 + NN * 16;             // NN*90
  float* h2  = h1 + NN * 90;             // NN*90
  float* h3  = h2 + NN * 90;             // NN*45
  float* agg = h3 + NN * 45;             // NN*90
  unsigned short* he_bf = (unsigned short*)(agg + NN * 90);   // NE*96
  unsigned short* wp1 = he_bf + (size_t)NE * 96;              // 48*96*40
  unsigned short* wp2 = wp1 + 48 * 96 * 40;                   // 270*96*40
  unsigned short* wp3 = wp2 + 270 * 96 * 40;                  // 270*48*40

  concat_kernel<<<(NN * 16) / 256, 256, 0, stream>>>(x, pos, h0);

  // W' preps (independent of edge data)
  wprep_kernel<<<(48 * 96 * 40) / 256, 256, 0, stream>>>(c1_w2, c1_b2, wp1, 16, 90, 96, 48 * 96 * 40);
  wprep_kernel<<<(270 * 96 * 40) / 256, 256, 0, stream>>>(c2_w2, c2_b2, wp2, 90, 90, 96, 270 * 96 * 40);
  wprep_kernel<<<(270 * 48 * 40) / 256, 256, 0, stream>>>(c3_w2, c3_b2, wp3, 90, 45, 48, 270 * 48 * 40);

  // conv1: 16 -> 90
  hipMemsetAsync(agg, 0, (size_t)NN * 90 * sizeof(float), stream);
  edge_mlp_bf<<<(NE * 96) / 256, 256, 0, stream>>>(ea, c1_w1, c1_b1, he_bf);
  msg_mfma<16, 90, 96, 2, 4, 24, 48><<<NE / 128, 256, 0, stream>>>(he_bf, h0, src, dst, wp1, agg);
  node_kernel<16, 90><<<(NN * 90) / 256, 256, 0, stream>>>(agg, h0, c1_root, c1_bias, h1);

  // conv2: 90 -> 90
  hipMemsetAsync(agg, 0, (size_t)NN * 90 * sizeof(float), stream);
  edge_mlp_bf<<<(NE * 96) / 256, 256, 0, stream>>>(ea, c2_w1, c2_b1, he_bf);
  msg_mfma<90, 90, 96, 2, 4, 104, 270><<<NE / 128, 256, 0, stream>>>(he_bf, h1, src, dst, wp2, agg);
  node_kernel<90, 90><<<(NN * 90) / 256, 256, 0, stream>>>(agg, h1, c2_root, c2_bias, h2);

  // conv3: 90 -> 45
  hipMemsetAsync(agg, 0, (size_t)NN * 45 * sizeof(float), stream);
  edge_mlp_bf<<<(NE * 96) / 256, 256, 0, stream>>>(ea, c3_w1, c3_b1, he_bf);
  msg_mfma<90, 45, 48, 1, 2, 104, 270><<<NE / 128, 256, 0, stream>>>(he_bf, h2, src, dst, wp3, agg);
  node_kernel<90, 45><<<(NN * 45 + 255) / 256, 256, 0, stream>>>(agg, h2, c3_root, c3_bias, h3);

  pool_mlp_kernel<<<NG, 128, 0, stream>>>(h3, batch, fc1_w, fc1_b, out_w, out_b, (float*)d_out);
}

// Round 3
// 839.481 us; speedup vs baseline: 8.4249x; 1.5998x over previous
//
#include <hip/hip_runtime.h>

#define NN 16000   // nodes
#define NE 64000   // edges
#define HD 90      // hidden
#define NG 512     // graphs

typedef float f32x4 __attribute__((ext_vector_type(4)));
typedef short s16x8 __attribute__((ext_vector_type(8)));

// round-half-up f32 -> bf16 (unbiased enough; truncation would bias sums low)
__device__ __forceinline__ unsigned short rhu1(float f) {
  return (unsigned short)((__builtin_bit_cast(unsigned int, f) + 0x8000u) >> 16);
}
// pack two f32 -> bf16x2 (lo in low half), RHU rounding, v_perm idiom
__device__ __forceinline__ unsigned int rhu_pack(float lo, float hi) {
  unsigned int ul = __builtin_bit_cast(unsigned int, lo) + 0x8000u;
  unsigned int uh = __builtin_bit_cast(unsigned int, hi) + 0x8000u;
  return __builtin_amdgcn_perm(uh, ul, 0x07060302u);  // [uh.b3 uh.b2 ul.b3 ul.b2]
}
__device__ __forceinline__ float bf2f(unsigned short b) {
  return __builtin_bit_cast(float, ((unsigned int)b) << 16);
}

// h0 = concat(x, pos) : [NN, 16]
__global__ void concat_kernel(const float* __restrict__ x, const float* __restrict__ pos,
                              float* __restrict__ h0) {
  int idx = blockIdx.x * 256 + threadIdx.x;
  if (idx >= NN * 16) return;
  int n = idx >> 4, c = idx & 15;
  h0[idx] = (c < 13) ? x[n * 13 + c] : pos[n * 3 + (c - 13)];
}

// he_bf[e][k] : [NE, 96] bf16. k<90: relu(edge MLP); k==90: 1.0 (bias row); k>90: 0
__global__ void edge_mlp_bf(const float* __restrict__ ea, const float* __restrict__ w1,
                            const float* __restrict__ b1, unsigned short* __restrict__ he) {
  int idx = blockIdx.x * 256 + threadIdx.x;
  if (idx >= NE * 96) return;
  int e = idx / 96, k = idx - e * 96;
  unsigned short v;
  if (k < 90) {
    const float* a = ea + e * 8;
    float acc = b1[k];
#pragma unroll
    for (int j = 0; j < 8; j++) acc = fmaf(a[j], w1[j * HD + k], acc);
    v = rhu1(fmaxf(acc, 0.f));
  } else {
    v = (k == 90) ? (unsigned short)0x3F80 : (unsigned short)0;  // bf16(1.0) / 0
  }
  he[idx] = v;
}

// W' prep: chunk-major bf16 [NC][OCP][40]; element (c,o,kk): k=c*32+kk (kk<32),
// i=k/96, hk=k%96; val = hk<90 ? w2[hk][i*OC+o] : hk==90 ? b2[i*OC+o] : 0
__global__ void wprep_kernel(const float* __restrict__ w2, const float* __restrict__ b2,
                             unsigned short* __restrict__ wout,
                             int IN_C, int OC, int OCP, int nelem) {
  int idx = blockIdx.x * 256 + threadIdx.x;
  if (idx >= nelem) return;
  int row = OCP * 40;
  int c = idx / row, r = idx - c * row;
  int o = r / 40, kk = r - o * 40;
  float v = 0.f;
  if (kk < 32 && o < OC) {
    int k = c * 32 + kk;
    int i = k / 96, hk = k - i * 96;
    if (hk < 90) v = w2[hk * (IN_C * OC) + i * OC + o];
    else if (hk == 90) v = b2[i * OC + o];
  }
  wout[idx] = rhu1(v);
}

// Fused message GEMM (bf16 MFMA) + scatter.
// Block: 128 edges x OCP outputs; 4 waves.
// K' = i*96 + hk (hk in [0,96): 90 he rows + bias row + pad); chunk = 32 K'.
// A[e][k'] = he[e][hk]*z[e][i]: he frags from LDS (he_s), z scalar from LDS, built per chunk.
// W' chunks double-buffered in LDS via VGPR loads + ds_write (L2-allocating, 64B-coalesced).
template <int IN_C, int OC, int OCP, int WNV, int WM, int NC>
__launch_bounds__(256, 2)
__global__ void msg_mfma(const unsigned short* __restrict__ he,
                         const float* __restrict__ nin,
                         const int* __restrict__ src, const int* __restrict__ dst,
                         const unsigned short* __restrict__ wp,
                         float* __restrict__ agg) {
  constexpr int WB = OCP * 40 * 2;          // bytes per W chunk (incl. 8-col pad)
  constexpr int NW16 = WB / 16;             // 16B packets per W chunk
  constexpr int NPT = (NW16 + 255) / 256;   // packets per thread
  constexpr int HS = 104;                   // he_s/z_s row stride (shorts): 208B -> bank stride 20, conflict-free
  __shared__ unsigned short he_s[128 * HS];
  __shared__ unsigned short z_s[128 * HS];
  __shared__ unsigned short w_s[2][OCP * 40];
  __shared__ int dst_s[128];
  const int tid = threadIdx.x;
  const int e0 = blockIdx.x * 128;
  const int wid = tid >> 6, ln = tid & 15, q = (tid & 63) >> 4;
  const int wn = wid % WNV, wm = wid / WNV;
  const int eb = wm * (WM * 16);
  const int n0w = wn * 48;

  if (tid < 128) dst_s[tid] = dst[e0 + tid];

  // stage he rows -> he_s (row stride HS shorts; 96 shorts = 12 x 16B per edge)
  for (int i = tid; i < 128 * 12; i += 256) {
    int e = i / 12, p = i - e * 12;
    *(uint4*)&he_s[e * HS + p * 8] = *(const uint4*)(he + (size_t)(e0 + e) * 96 + p * 8);
  }
  // gather z = nin[src[e]] -> bf16 rows z_s[e][i]
  constexpr int PAIRS = IN_C / 2;
  for (int i2 = tid; i2 < 128 * PAIRS; i2 += 256) {
    int e = i2 / PAIRS, p = i2 - e * PAIRS;
    const float2 v = *(const float2*)(nin + (size_t)src[e0 + e] * IN_C + 2 * p);
    *(unsigned int*)&z_s[e * HS + 2 * p] = rhu_pack(v.x, v.y);
  }
  // W chunk 0: global -> regs -> LDS buf0
  uint4 wreg[NPT];
#pragma unroll
  for (int p = 0; p < NPT; p++) {
    int t = tid + p * 256;
    if (t < NW16) wreg[p] = *(const uint4*)((const char*)wp + t * 16);
  }
#pragma unroll
  for (int p = 0; p < NPT; p++) {
    int t = tid + p * 256;
    if (t < NW16) *(uint4*)((char*)&w_s[0][0] + t * 16) = wreg[p];
  }
  __syncthreads();

  f32x4 acc[WM][3];
#pragma unroll
  for (int mt = 0; mt < WM; mt++)
#pragma unroll
    for (int nt = 0; nt < 3; nt++) acc[mt][nt] = (f32x4)0.f;

  float zf[WM];
  int sub = 0, iidx = 0;
  for (int c = 0; c < NC; c++) {
    const int buf = c & 1;
    // prefetch next W chunk into registers (in flight across the MFMA block)
    if (c + 1 < NC) {
      const char* wg = (const char*)wp + (size_t)(c + 1) * WB;
#pragma unroll
      for (int p = 0; p < NPT; p++) {
        int t = tid + p * 256;
        if (t < NW16) wreg[p] = *(const uint4*)(wg + t * 16);
      }
    }
    if (sub == 0) {
#pragma unroll
      for (int mt = 0; mt < WM; mt++)
        zf[mt] = bf2f(z_s[(eb + mt * 16 + ln) * HS + iidx]);
    }
    // A-frags: he frag (LDS) * z, RHU-round, pack
    union { unsigned int u[4]; s16x8 v; } af[WM];
#pragma unroll
    for (int mt = 0; mt < WM; mt++) {
      const uint4 u = *(const uint4*)&he_s[(eb + mt * 16 + ln) * HS + sub * 32 + q * 8];
      float h0 = __builtin_bit_cast(float, u.x << 16);
      float h1 = __builtin_bit_cast(float, u.x & 0xFFFF0000u);
      float h2 = __builtin_bit_cast(float, u.y << 16);
      float h3 = __builtin_bit_cast(float, u.y & 0xFFFF0000u);
      float h4 = __builtin_bit_cast(float, u.z << 16);
      float h5 = __builtin_bit_cast(float, u.z & 0xFFFF0000u);
      float h6 = __builtin_bit_cast(float, u.w << 16);
      float h7 = __builtin_bit_cast(float, u.w & 0xFFFF0000u);
      af[mt].u[0] = rhu_pack(h0 * zf[mt], h1 * zf[mt]);
      af[mt].u[1] = rhu_pack(h2 * zf[mt], h3 * zf[mt]);
      af[mt].u[2] = rhu_pack(h4 * zf[mt], h5 * zf[mt]);
      af[mt].u[3] = rhu_pack(h6 * zf[mt], h7 * zf[mt]);
    }
#pragma unroll
    for (int nt = 0; nt < 3; nt++) {
      const s16x8 bfr = *(const s16x8*)&w_s[buf][(n0w + nt * 16 + ln) * 40 + q * 8];
#pragma unroll
      for (int mt = 0; mt < WM; mt++)
        acc[mt][nt] = __builtin_amdgcn_mfma_f32_16x16x32_bf16(af[mt].v, bfr, acc[mt][nt], 0, 0, 0);
    }
    // write prefetched chunk c+1 into the other buffer (reads of it were fenced
    // by the barrier at the end of iter c-1), then barrier
    if (c + 1 < NC) {
#pragma unroll
      for (int p = 0; p < NPT; p++) {
        int t = tid + p * 256;
        if (t < NW16) *(uint4*)((char*)&w_s[buf ^ 1][0] + t * 16) = wreg[p];
      }
    }
    __syncthreads();
    if (++sub == 3) { sub = 0; ++iidx; }
  }

  // epilogue: D[row=q*4+r][col=ln] -> atomicAdd agg[dst]
#pragma unroll
  for (int mt = 0; mt < WM; mt++) {
#pragma unroll
    for (int nt = 0; nt < 3; nt++) {
      int o = n0w + nt * 16 + ln;
      if (o < OC) {
#pragma unroll
        for (int r = 0; r < 4; r++) {
          int el = eb + mt * 16 + q * 4 + r;
          atomicAdd(agg + (size_t)dst_s[el] * OC + o, acc[mt][nt][r]);
        }
      }
    }
  }
}

// out[n][o] = relu(agg[n][o] + sum_i nin[n][i]*root[i][o] + bias[o])   (fp32 exact)
template <int IN_C, int OC>
__global__ void node_kernel(const float* __restrict__ agg, const float* __restrict__ nin,
                            const float* __restrict__ root, const float* __restrict__ bias,
                            float* __restrict__ out) {
  int idx = blockIdx.x * 256 + threadIdx.x;
  if (idx >= NN * OC) return;
  int n = idx / OC, o = idx - n * OC;
  float acc = agg[idx] + bias[o];
  const float* inp = nin + (size_t)n * IN_C;
#pragma unroll 6
  for (int i = 0; i < IN_C; i++) acc = fmaf(inp[i], root[i * OC + o], acc);
  out[idx] = fmaxf(acc, 0.f);
}

// per-graph: pool (batch sorted -> binary search) + fc1 + out
__global__ void pool_mlp_kernel(const float* __restrict__ h3, const int* __restrict__ batch,
                                const float* __restrict__ fc1_w, const float* __restrict__ fc1_b,
                                const float* __restrict__ out_w, const float* __restrict__ out_b,
                                float* __restrict__ out) {
  const int b = blockIdx.x;
  const int tid = threadIdx.x;
  __shared__ float g[45];
  __shared__ float go[90];
  __shared__ int rng[2];
  if (tid < 2) {
    int target = b + tid;
    int lo = 0, hi = NN;
    while (lo < hi) { int mid = (lo + hi) >> 1; if (batch[mid] < target) lo = mid + 1; else hi = mid; }
    rng[tid] = lo;
  }
  __syncthreads();
  const int s = rng[0], e = rng[1];
  if (tid < 45) {
    float acc = 0.f;
    for (int n = s; n < e; n++) acc += h3[n * 45 + tid];
    g[tid] = acc;
  }
  __syncthreads();
  if (tid < 90) {
    float acc = fc1_b[tid];
#pragma unroll 5
    for (int i = 0; i < 45; i++) acc = fmaf(g[i], fc1_w[i * 90 + tid], acc);
    go[tid] = fmaxf(acc, 0.f) * out_w[tid];
  }
  __syncthreads();
  if (tid == 0) {
    float acc = out_b[0];
    for (int i = 0; i < 90; i++) acc += go[i];
    out[b] = acc;
  }
}

extern "C" void kernel_launch(void* const* d_in, const int* in_sizes, int n_in,
                              void* d_out, int out_size, void* d_ws, size_t ws_size,
                              hipStream_t stream) {
  const float* x       = (const float*)d_in[0];
  const float* pos     = (const float*)d_in[1];
  const float* ea      = (const float*)d_in[2];
  const int*   eidx    = (const int*)d_in[3];
  const int*   batch   = (const int*)d_in[4];
  const float* c1_w1   = (const float*)d_in[5];
  const float* c1_b1   = (const float*)d_in[6];
  const float* c1_w2   = (const float*)d_in[7];
  const float* c1_b2   = (const float*)d_in[8];
  const float* c1_root = (const float*)d_in[9];
  const float* c1_bias = (const float*)d_in[10];
  const float* c2_w1   = (const float*)d_in[11];
  const float* c2_b1   = (const float*)d_in[12];
  const float* c2_w2   = (const float*)d_in[13];
  const float* c2_b2   = (const float*)d_in[14];
  const float* c2_root = (const float*)d_in[15];
  const float* c2_bias = (const float*)d_in[16];
  const float* c3_w1   = (const float*)d_in[17];
  const float* c3_b1   = (const float*)d_in[18];
  const float* c3_w2   = (const float*)d_in[19];
  const float* c3_b2   = (const float*)d_in[20];
  const float* c3_root = (const float*)d_in[21];
  const float* c3_bias = (const float*)d_in[22];
  const float* fc1_w   = (const float*)d_in[23];
  const float* fc1_b   = (const float*)d_in[24];
  const float* out_w   = (const float*)d_in[25];
  const float* out_b   = (const float*)d_in[26];
  const int* src = eidx;
  const int* dst = eidx + NE;

  // workspace carve (f32 units, then u16 region)
  float* ws  = (float*)d_ws;
  float* h0  = ws;                       // NN*16
  float* h1  = h0 + NN * 16;             // NN*90
  float* h2  = h1 + NN * 90;             // NN*90
  float* h3  = h2 + NN * 90;             // NN*45
  float* agg = h3 + NN * 45;             // NN*90
  unsigned short* he_bf = (unsigned short*)(agg + NN * 90);   // NE*96
  unsigned short* wp1 = he_bf + (size_t)NE * 96;              // 48*96*40
  unsigned short* wp2 = wp1 + 48 * 96 * 40;                   // 270*96*40
  unsigned short* wp3 = wp2 + 270 * 96 * 40;                  // 270*48*40

  concat_kernel<<<(NN * 16) / 256, 256, 0, stream>>>(x, pos, h0);

  // W' preps (independent of edge data)
  wprep_kernel<<<(48 * 96 * 40) / 256, 256, 0, stream>>>(c1_w2, c1_b2, wp1, 16, 90, 96, 48 * 96 * 40);
  wprep_kernel<<<(270 * 96 * 40) / 256, 256, 0, stream>>>(c2_w2, c2_b2, wp2, 90, 90, 96, 270 * 96 * 40);
  wprep_kernel<<<(270 * 48 * 40) / 256, 256, 0, stream>>>(c3_w2, c3_b2, wp3, 90, 45, 48, 270 * 48 * 40);

  // conv1: 16 -> 90
  hipMemsetAsync(agg, 0, (size_t)NN * 90 * sizeof(float), stream);
  edge_mlp_bf<<<(NE * 96) / 256, 256, 0, stream>>>(ea, c1_w1, c1_b1, he_bf);
  msg_mfma<16, 90, 96, 2, 4, 48><<<NE / 128, 256, 0, stream>>>(he_bf, h0, src, dst, wp1, agg);
  node_kernel<16, 90><<<(NN * 90) / 256, 256, 0, stream>>>(agg, h0, c1_root, c1_bias, h1);

  // conv2: 90 -> 90
  hipMemsetAsync(agg, 0, (size_t)NN * 90 * sizeof(float), stream);
  edge_mlp_bf<<<(NE * 96) / 256, 256, 0, stream>>>(ea, c2_w1, c2_b1, he_bf);
  msg_mfma<90, 90, 96, 2, 4, 270><<<NE / 128, 256, 0, stream>>>(he_bf, h1, src, dst, wp2, agg);
  node_kernel<90, 90><<<(NN * 90) / 256, 256, 0, stream>>>(agg, h1, c2_root, c2_bias, h2);

  // conv3: 90 -> 45
  hipMemsetAsync(agg, 0, (size_t)NN * 45 * sizeof(float), stream);
  edge_mlp_bf<<<(NE * 96) / 256, 256, 0, stream>>>(ea, c3_w1, c3_b1, he_bf);
  msg_mfma<90, 45, 48, 1, 2, 270><<<NE / 128, 256, 0, stream>>>(he_bf, h2, src, dst, wp3, agg);
  node_kernel<90, 45><<<(NN * 45 + 255) / 256, 256, 0, stream>>>(agg, h2, c3_root, c3_bias, h3);

  pool_mlp_kernel<<<NG, 128, 0, stream>>>(h3, batch, fc1_w, fc1_b, out_w, out_b, (float*)d_out);
}